// Round 1
// 186.842 us; speedup vs baseline: 1.1496x; 1.1496x over previous
//
#include <hip/hip_runtime.h>
#include <hip/hip_bf16.h>
#include <math.h>

#define BB 8
#define NN 2048
#define DD 128
#define LL 3
#define GN_EPS 1e-5f

typedef __attribute__((ext_vector_type(8))) short bf16x8;
typedef __attribute__((ext_vector_type(4))) float f32x4;
typedef __attribute__((ext_vector_type(8))) unsigned short u16x8;

// raw v_sqrt_f32 (1 inst)
#define FSQRT(x) __builtin_amdgcn_sqrtf(x)

#define GLL16(gp, lp) __builtin_amdgcn_global_load_lds( \
    (const __attribute__((address_space(1))) void*)(gp), \
    (__attribute__((address_space(3))) void*)(lp), 16, 0, 0)

// s_waitcnt imm: vm_lo[3:0], exp[6:4], lgkm[11:8], vm_hi[15:14]
#define WAIT_VM12 0x0F7C   // vmcnt(12), lgkm/exp nowait

// round-half-up f32 -> bf16 bits
__device__ __forceinline__ unsigned short f2bf(float f) {
    union { float f; unsigned u; } v; v.f = f;
    return (unsigned short)((v.u + 0x8000u) >> 16);
}

__device__ __forceinline__ float fast_tanh(float x) {
    float e = __expf(-2.0f * fabsf(x));
    float t = (1.0f - e) * __builtin_amdgcn_rcpf(1.0f + e);
    return copysignf(t, x);
}

// GraphNorm affine fold: h_norm = s*h + c
__device__ __forceinline__ void stats_sc(float ps, float pq, float a, float w_,
                                         float b_, float& s, float& c) {
    const float inv_n = 1.0f / (float)NN;
    float mean = ps * inv_n;
    float msq  = pq * inv_n;
    float var  = msq - mean * mean * a * (2.0f - a);
    float rstd = rsqrtf(var + GN_EPS);
    s = w_ * rstd;
    c = b_ - s * (a * mean);
}

// Packed layouts (16B granule = one lane's bf16x8 frag slice):
//  Ap[b][ntile(128)][kcg(64)][lane(64)]  value[j] = dist(ntile*16+ll, kcg*32+lq*8+j)
//  tp[b][kcg(64)][dt(8)][lane(64)]       value[j] = dinv*lin(h)[d=dt*16+ll][m=kcg*32+lq*8+j]

// ---------------------------------------------------------------------------
// K0: prep_wg — pack Wg (3x128x128 f32) into bf16 MFMA frag order.
// Block 0 additionally folds layer-0 lin: Weff = Wg0·Wn (128x2, f32),
// beff = Wg0·bn — lets gen_pack emit tp0 directly (lin0 kernel removed).
// ---------------------------------------------------------------------------
__global__ __launch_bounds__(256)
void prep_wg(const float* __restrict__ Wg, const float* __restrict__ Wn,
             const float* __restrict__ bn, unsigned short* __restrict__ wgf,
             float* __restrict__ weff, float* __restrict__ beff)
{
    const int f = blockIdx.x * 256 + threadIdx.x;    // < 3*128*128
    const int l  = f >> 14;
    const int r  = f & 16383;
    const int dp = r >> 7;
    const int e  = r & 127;
    const int dpt = dp >> 4, ll = dp & 15;
    const int kc  = e >> 5,  eo = e & 31;
    wgf[((((l * 8 + dpt) * 4 + kc) * 16 + ll) << 5) + eo] = f2bf(Wg[f]);

    if (blockIdx.x == 0 && threadIdx.x < 128) {
        const int ee = threadIdx.x;
        float a0 = 0.f, a1 = 0.f, cc = 0.f;
        for (int d = 0; d < 128; ++d) {
            const float wv = Wg[ee * 128 + d];       // layer 0 slice
            a0 = fmaf(wv, Wn[d * 2 + 0], a0);
            a1 = fmaf(wv, Wn[d * 2 + 1], a1);
            cc = fmaf(wv, bn[d], cc);
        }
        weff[ee * 2 + 0] = a0;
        weff[ee * 2 + 1] = a1;
        beff[ee] = cc;
    }
}

// ---------------------------------------------------------------------------
// K1: gen_pack — A (dist+I, bf16) in agg's frag-linear order, dinv, proj_node
// h-init, AND tp0 (layer-0 lin folded via Weff/beff: tp0 = dinv*(x·Weff+beff)).
// grid 1024 = [ntile(7b)<<3 | b(3b)].
// ---------------------------------------------------------------------------
__global__ __launch_bounds__(256)
void gen_pack(const float* __restrict__ inst, const float* __restrict__ Wn,
              const float* __restrict__ bn, const float* __restrict__ weff,
              const float* __restrict__ beff, unsigned short* __restrict__ Ap,
              float* __restrict__ dinv, float* __restrict__ h,
              unsigned short* __restrict__ tp,
              float* __restrict__ psum, float* __restrict__ psq)
{
    __shared__ float cs[NN * 2];          // 16 KB coords
    __shared__ float part[4][16];
    const int b     = blockIdx.x & 7;
    const int ntile = blockIdx.x >> 3;    // 0..127
    const int n0    = ntile * 16;
    const int tid   = threadIdx.x;
    const int w     = tid >> 6;
    const int lane  = tid & 63;
    const int lq    = lane >> 4;
    const int ll    = lane & 15;

    const float* instb = inst + b * NN * 2;
    for (int i = tid; i < (NN * 2) / 4; i += 256)
        ((float4*)cs)[i] = ((const float4*)instb)[i];
    __syncthreads();

    const int n = n0 + ll;
    const float nx = cs[n * 2 + 0];
    const float ny = cs[n * 2 + 1];

    u16x8* apw = (u16x8*)Ap + (size_t)(b * 128 + ntile) * 64 * 64 + (w * 16) * 64 + lane;

    const int diagkcg = ntile >> 1;       // kcg whose m-range contains n0..n0+15
    float rs = 0.f;
    for (int kc = 0; kc < 16; ++kc) {
        const int kcg = w * 16 + kc;
        const int mb  = kcg * 32 + lq * 8;
        const float* cp = &cs[mb * 2];
        float4 c01 = *(const float4*)(cp + 0);
        float4 c23 = *(const float4*)(cp + 4);
        float4 c45 = *(const float4*)(cp + 8);
        float4 c67 = *(const float4*)(cp + 12);
        float mxx[8] = { c01.x, c01.z, c23.x, c23.z, c45.x, c45.z, c67.x, c67.z };
        float myy[8] = { c01.y, c01.w, c23.y, c23.w, c45.y, c45.w, c67.y, c67.w };
        float dist[8];
        #pragma unroll
        for (int j = 0; j < 8; ++j) {
            float dx = nx - mxx[j];
            float dy = ny - myy[j];
            dist[j] = FSQRT(dx * dx + dy * dy);
        }
        if (kcg == diagkcg) {
            #pragma unroll
            for (int j = 0; j < 8; ++j)
                if (mb + j == n) dist[j] = 1.0f;       // self-loop
        }
        u16x8 pk;
        #pragma unroll
        for (int j = 0; j < 8; ++j) {
            pk[j] = f2bf(dist[j]);
            rs += dist[j];
        }
        apw[kc * 64] = pk;
    }

    rs += __shfl_xor(rs, 16);
    rs += __shfl_xor(rs, 32);
    if (lq == 0) part[w][ll] = rs;
    __syncthreads();
    if (tid < 16)
        dinv[b * NN + n0 + tid] = rsqrtf(part[0][tid] + part[1][tid] +
                                         part[2][tid] + part[3][tid]);

    // fused proj h-init + tp0 (layer-0 lin folded, dinv from part[])
    {
        const int d  = tid & 127;
        const int r0 = tid >> 7;          // 0/1
        const float w0 = Wn[d * 2 + 0];
        const float w1 = Wn[d * 2 + 1];
        const float bv = bn[d];
        const float we0 = weff[d * 2 + 0];
        const float we1 = weff[d * 2 + 1];
        const float be  = beff[d];
        const int kcg   = ntile >> 1;
        const int mbase = (ntile & 1) * 16;
        const int dt    = d >> 4;
        const int lld   = d & 15;
        unsigned short* tpd =
            tp + (((size_t)(b * 64 + kcg) * 8 + dt) * 64 + lld) * 8;
        #pragma unroll
        for (int r = r0; r < 16; r += 2) {
            const float x0 = cs[(n0 + r) * 2 + 0];
            const float x1 = cs[(n0 + r) * 2 + 1];
            h[((size_t)b * NN + n0 + r) * DD + d] = fmaf(x0, w0, fmaf(x1, w1, bv));
            const float dv = rsqrtf(part[0][r] + part[1][r] + part[2][r] + part[3][r]);
            const int mloc = mbase + r;
            const int lqa  = mloc >> 3;
            const int j    = mloc & 7;
            tpd[(size_t)lqa * 128 + j] = f2bf(dv * fmaf(x0, we0, fmaf(x1, we1, be)));
        }
    }
    if (blockIdx.x == 0) {
        for (int i = tid; i < LL * BB * DD; i += 256) { psum[i] = 0.f; psq[i] = 0.f; }
    }
}

// ---------------------------------------------------------------------------
// K3: lin (MFMA).  Writes tp in agg's packed frag order.  (layers 1,2 only)
// blockIdx = [tile(6b)<<3 | b(3b)] (batch -> XCD, same as agg).
// ---------------------------------------------------------------------------
template <bool HP>
__global__ __launch_bounds__(256)
void lin_mfma(const float* __restrict__ h, const unsigned short* __restrict__ wgf_l,
              const float* __restrict__ dinv,
              const float* __restrict__ psumP, const float* __restrict__ psqP,
              const float* __restrict__ ga, const float* __restrict__ gw,
              const float* __restrict__ gb, unsigned short* __restrict__ tp)
{
    __shared__ float sL[DD], cL[DD];
    const int tid  = threadIdx.x;
    const int b    = blockIdx.x & 7;
    const int tile = blockIdx.x >> 3;
    const int row0 = b * NN + tile * 32;
    const int w    = tid >> 6;
    const int lane = tid & 63;
    const int lq   = lane >> 4;
    const int ll   = lane & 15;

    if (tid < DD) {
        float s = 1.0f, c = 0.0f;
        if (HP)
            stats_sc(psumP[b * DD + tid], psqP[b * DD + tid],
                     ga[tid], gw[tid], gb[tid], s, c);
        sL[tid] = s; cL[tid] = c;
    }
    __syncthreads();

    bf16x8 aw[2][4];
    #pragma unroll
    for (int mt = 0; mt < 2; ++mt) {
        const int dpt = 2 * w + mt;
        #pragma unroll
        for (int kc = 0; kc < 4; ++kc)
            aw[mt][kc] = *(const bf16x8*)&wgf_l[(((dpt * 4 + kc) * 16 + ll) << 5) + lq * 8];
    }

    bf16x8 bh[2][4];
    #pragma unroll
    for (int nt = 0; nt < 2; ++nt) {
        const float* hrow = h + (size_t)(row0 + nt * 16 + ll) * DD;
        #pragma unroll
        for (int kc = 0; kc < 4; ++kc) {
            float4 h0 = *(const float4*)&hrow[kc * 32 + lq * 8];
            float4 h1 = *(const float4*)&hrow[kc * 32 + lq * 8 + 4];
            const int e0 = kc * 32 + lq * 8;
            bf16x8 p;
            p[0] = (short)f2bf(fmaf(sL[e0 + 0], h0.x, cL[e0 + 0]));
            p[1] = (short)f2bf(fmaf(sL[e0 + 1], h0.y, cL[e0 + 1]));
            p[2] = (short)f2bf(fmaf(sL[e0 + 2], h0.z, cL[e0 + 2]));
            p[3] = (short)f2bf(fmaf(sL[e0 + 3], h0.w, cL[e0 + 3]));
            p[4] = (short)f2bf(fmaf(sL[e0 + 4], h1.x, cL[e0 + 4]));
            p[5] = (short)f2bf(fmaf(sL[e0 + 5], h1.y, cL[e0 + 5]));
            p[6] = (short)f2bf(fmaf(sL[e0 + 6], h1.z, cL[e0 + 6]));
            p[7] = (short)f2bf(fmaf(sL[e0 + 7], h1.w, cL[e0 + 7]));
            bh[nt][kc] = p;
        }
    }

    f32x4 acc[2][2];   // [nt][mt]
    #pragma unroll
    for (int i = 0; i < 2; ++i)
        #pragma unroll
        for (int j = 0; j < 2; ++j) acc[i][j] = (f32x4)0.0f;

    #pragma unroll
    for (int kc = 0; kc < 4; ++kc)
        #pragma unroll
        for (int nt = 0; nt < 2; ++nt)
            #pragma unroll
            for (int mt = 0; mt < 2; ++mt)
                acc[nt][mt] = __builtin_amdgcn_mfma_f32_16x16x32_bf16(
                    bh[nt][kc], aw[mt][kc], acc[nt][mt], 0, 0, 0);

    // packed store: value (dp=(2w+mt)*16+ll, m = tile*32+nt*16+lq*4+reg)
    #pragma unroll
    for (int nt = 0; nt < 2; ++nt) {
        const int mloc0 = nt * 16 + lq * 4;            // m within the kcg=tile chunk
        const int lq_a  = mloc0 >> 3;
        const int j0    = mloc0 & 7;
        float4 di4 = *(const float4*)&dinv[row0 + mloc0];
        #pragma unroll
        for (int mt = 0; mt < 2; ++mt) {
            const int dt = 2 * w + mt;
            ushort4 pk;
            pk.x = f2bf(acc[nt][mt][0] * di4.x);
            pk.y = f2bf(acc[nt][mt][1] * di4.y);
            pk.z = f2bf(acc[nt][mt][2] * di4.z);
            pk.w = f2bf(acc[nt][mt][3] * di4.w);
            *(ushort4*)&tp[((size_t)((b * 64 + tile) * 8 + dt) * 64 + lq_a * 16 + ll) * 8 + j0] = pk;
        }
    }
}

// ---------------------------------------------------------------------------
// K4: agg — 32n x 128d tile (BM=32), grid 512, 2 blocks/CU, 100% resident.
// B (tp) frags are dt-only: reused for both n-tiles in-register, so L2 tp
// traffic halves vs BM=16 (64->32 MB/XCD per agg).  A staged via GLL ring of
// 7 chunk-tiles (8 KB each = 2 ntiles x 4 frags), prefetch distance 6.  Per
// phase vm ops = 2 A-GLL + 8 B; steady queue at iter top = 22 ->
// vmcnt(12) drains exactly A(k+3)x2 + B(k)x8 (A(k) drained 3 iters prior).
// Raw s_barrier (no drain).  Waves d-split (dt {2w,2w+1}), full K each.
// ---------------------------------------------------------------------------
template <bool HP>
__global__ __launch_bounds__(256, 2)
void agg_mfma(const unsigned short* __restrict__ Ap, const unsigned short* __restrict__ tp,
              const float* __restrict__ dinv, const float* __restrict__ bg_l,
              const float* __restrict__ psumP, const float* __restrict__ psqP,
              const float* __restrict__ ga, const float* __restrict__ gw,
              const float* __restrict__ gb,
              float* __restrict__ h, float* __restrict__ psum, float* __restrict__ psq)
{
    __shared__ char Abuf[7][8192];        // 56 KB: ring of 7 chunk-tiles (2 nt x 4 frags)
    const int b     = blockIdx.x & 7;
    const int t2    = blockIdx.x >> 3;    // 0..63 (32-row tile)
    const int n0    = t2 * 32;
    const int tid   = threadIdx.x;
    const int w     = tid >> 6;
    const int lane  = tid & 63;
    const int lq    = lane >> 4;
    const int ll    = lane & 15;

    // per-lane packed sources; ntile stride in Ap = 64*512 = 32768 shorts
    const unsigned short* apsrc = Ap + ((size_t)(b * 128 + t2 * 2) * 64) * 512 + lane * 8;
    const unsigned short* tpb   = tp + ((size_t)b * 64 * 8) * 512 + lane * 8;

    f32x4 acc[2][2];   // [nt][dtl]
    acc[0][0] = (f32x4)0.0f; acc[0][1] = (f32x4)0.0f;
    acc[1][0] = (f32x4)0.0f; acc[1][1] = (f32x4)0.0f;

    bf16x8 fb[3][2][4];   // [ringbuf][dtl][s] — dt-only, shared across both nt

#define GLLA(c) { \
        GLL16(apsrc + (size_t)((((c) & 15) * 4 + w)) * 512, \
              &Abuf[(c) % 7][w * 1024]); \
        GLL16(apsrc + (size_t)((((c) & 15) * 4 + w)) * 512 + 32768, \
              &Abuf[(c) % 7][4096 + w * 1024]); \
    }
#define LOADB(c) { \
        const int kb_ = ((c) & 15) * 4; \
        _Pragma("unroll") \
        for (int s_ = 0; s_ < 4; ++s_) { \
            fb[(c) % 3][0][s_] = *(const bf16x8*)(tpb + (size_t)((kb_ + s_) * 8 + 2 * w + 0) * 512); \
            fb[(c) % 3][1][s_] = *(const bf16x8*)(tpb + (size_t)((kb_ + s_) * 8 + 2 * w + 1) * 512); \
        } \
    }

    // prologue — queue: A0x2 A1x2 A2x2 A3x2 B0x8 A4x2 B1x8 A5x2 = 28.
    // iter0 vmcnt(12) drains 16 = A0..A3 + B0 (both needed), leaves 12.
    GLLA(0) GLLA(1) GLLA(2) GLLA(3)
    LOADB(0)
    GLLA(4)
    LOADB(1)
    GLLA(5)

    #pragma unroll
    for (int k = 0; k < 16; ++k) {
        __builtin_amdgcn_s_waitcnt(WAIT_VM12); // A(k) in LDS, B(k) in regs; rest in flight
        __builtin_amdgcn_s_barrier();          // all waves' A(k) in LDS
        __builtin_amdgcn_sched_barrier(0);
        bf16x8 af[2][4];
        const char* lb = &Abuf[k % 7][0];
        #pragma unroll
        for (int nt = 0; nt < 2; ++nt)
            #pragma unroll
            for (int s = 0; s < 4; ++s)
                af[nt][s] = *(const bf16x8*)(lb + nt * 4096 + s * 1024 + lane * 16);
        LOADB(k + 2)                           // B first, then A: queue order fixed
        GLLA(k + 6)
        __builtin_amdgcn_sched_barrier(0);
        #pragma unroll
        for (int s = 0; s < 4; ++s) {
            #pragma unroll
            for (int nt = 0; nt < 2; ++nt) {
                acc[nt][0] = __builtin_amdgcn_mfma_f32_16x16x32_bf16(fb[k % 3][0][s], af[nt][s], acc[nt][0], 0, 0, 0);
                acc[nt][1] = __builtin_amdgcn_mfma_f32_16x16x32_bf16(fb[k % 3][1][s], af[nt][s], acc[nt][1], 0, 0, 0);
            }
        }
    }
#undef GLLA
#undef LOADB

    // ---- per-wave epilogue: lane holds n = n0+nt*16+ll, d = (2w+dtl)*16+lq*4+reg
    const float di0 = dinv[b * NN + n0 + ll];
    const float di1 = dinv[b * NN + n0 + 16 + ll];
    #pragma unroll
    for (int dtl = 0; dtl < 2; ++dtl) {
        const int d0 = (2 * w + dtl) * 16 + lq * 4;
        float4 bg4 = *(const float4*)&bg_l[d0];
        float sres[4] = {1.f, 1.f, 1.f, 1.f}, cres[4] = {0.f, 0.f, 0.f, 0.f};
        if (HP) {
            float4 ps4 = *(const float4*)&psumP[b * DD + d0];
            float4 pq4 = *(const float4*)&psqP[b * DD + d0];
            float4 ga4 = *(const float4*)&ga[d0];
            float4 gw4 = *(const float4*)&gw[d0];
            float4 gb4 = *(const float4*)&gb[d0];
            stats_sc(ps4.x, pq4.x, ga4.x, gw4.x, gb4.x, sres[0], cres[0]);
            stats_sc(ps4.y, pq4.y, ga4.y, gw4.y, gb4.y, sres[1], cres[1]);
            stats_sc(ps4.z, pq4.z, ga4.z, gw4.z, gb4.z, sres[2], cres[2]);
            stats_sc(ps4.w, pq4.w, ga4.w, gw4.w, gb4.w, sres[3], cres[3]);
        }
        float hs[4] = {0.f, 0.f, 0.f, 0.f}, hq[4] = {0.f, 0.f, 0.f, 0.f};
        #pragma unroll
        for (int nt = 0; nt < 2; ++nt) {
            const int n = n0 + nt * 16 + ll;
            const float di = nt ? di1 : di0;
            size_t idx = ((size_t)b * NN + n) * DD + d0;
            float4 hv = *(const float4*)&h[idx];
            float outv[4];
            #pragma unroll
            for (int r = 0; r < 4; ++r) {
                float pre = di * acc[nt][dtl][r] + (&bg4.x)[r];
                outv[r] = fast_tanh(pre) + fmaf(sres[r], (&hv.x)[r], cres[r]);
                hs[r] += outv[r];
                hq[r] += outv[r] * outv[r];
            }
            float4 ov = { outv[0], outv[1], outv[2], outv[3] };
            *(float4*)&h[idx] = ov;
        }

        // stats: reduce over the 16 ll lanes (32 n's already folded across nt)
        #pragma unroll
        for (int off = 1; off < 16; off <<= 1) {
            #pragma unroll
            for (int r = 0; r < 4; ++r) {
                hs[r] += __shfl_xor(hs[r], off);
                hq[r] += __shfl_xor(hq[r], off);
            }
        }
        if (ll == 0) {
            #pragma unroll
            for (int r = 0; r < 4; ++r) {
                atomicAdd(&psum[b * DD + d0 + r], hs[r]);
                atomicAdd(&psq[b * DD + d0 + r], hq[r]);
            }
        }
    }
}

// ---------------------------------------------------------------------------
// K5: final apply with in-thread stats from layer-2 buffers
// ---------------------------------------------------------------------------
__global__ __launch_bounds__(256)
void apply_kernel(const float* __restrict__ h,
                  const float* __restrict__ psum2, const float* __restrict__ psq2,
                  const float* __restrict__ ga, const float* __restrict__ gw,
                  const float* __restrict__ gb, float* __restrict__ dst)
{
    const int i4 = blockIdx.x * 256 + threadIdx.x;    // < B*N*D/4
    const int dg = (i4 & 31) * 4;
    const int b  = i4 >> 16;                          // N*D/4 = 65536
    float4 hv = ((const float4*)h)[i4];
    float o[4];
    #pragma unroll
    for (int j = 0; j < 4; ++j) {
        const int d = dg + j;
        float s, c;
        stats_sc(psum2[b * DD + d], psq2[b * DD + d], ga[d], gw[d], gb[d], s, c);
        o[j] = fmaf(s, (&hv.x)[j], c);
    }
    float4 ov = { o[0], o[1], o[2], o[3] };
    ((float4*)dst)[i4] = ov;
}

// ---------------------------------------------------------------------------
extern "C" void kernel_launch(void* const* d_in, const int* in_sizes, int n_in,
                              void* d_out, int out_size, void* d_ws, size_t ws_size,
                              hipStream_t stream)
{
    const float* inst = (const float*)d_in[0];
    const float* Wn   = (const float*)d_in[1];
    const float* bn   = (const float*)d_in[2];
    const float* Wg   = (const float*)d_in[3];
    const float* bg   = (const float*)d_in[4];
    const float* gw   = (const float*)d_in[5];
    const float* gb   = (const float*)d_in[6];
    const float* ga   = (const float*)d_in[7];
    float* out = (float*)d_out;

    float* ws   = (float*)d_ws;
    float* dinv = ws;                                   // B*N
    float* h    = dinv + BB * NN;                       // B*N*D
    float* psum = h + (size_t)BB * NN * DD;             // LL*B*D
    float* psq  = psum + LL * BB * DD;                  // LL*B*D
    float* weff = psq + LL * BB * DD;                   // 256 (Wg0·Wn fold)
    float* beff = weff + 2 * DD;                        // 128
    unsigned short* wgf = (unsigned short*)(beff + DD); // LL*D*D bf16
    unsigned short* tp  = wgf + LL * DD * DD;           // B*D*N bf16 (4MB)
    unsigned short* Ap  = tp + (size_t)BB * DD * NN;    // B*N*N bf16 (64MB)

    prep_wg<<<(LL * DD * DD) / 256, 256, 0, stream>>>(Wg, Wn, bn, wgf, weff, beff);
    gen_pack<<<1024, 256, 0, stream>>>(inst, Wn, bn, weff, beff, Ap, dinv, h, tp, psum, psq);

    // layer 0: tp0 already produced by gen_pack (lin0 folded)
    agg_mfma<false><<<512, 256, 0, stream>>>(
        Ap, tp, dinv, bg + 0 * DD, nullptr, nullptr, ga, gw, gb, h, psum, psq);

    for (int l = 1; l < LL; ++l) {
        const unsigned short* wgl = wgf + (size_t)l * DD * DD;
        const float* psP = psum + (size_t)(l - 1) * BB * DD;
        const float* pqP = psq  + (size_t)(l - 1) * BB * DD;
        float* psL = psum + (size_t)l * BB * DD;
        float* pqL = psq  + (size_t)l * BB * DD;
        lin_mfma<true><<<(BB * NN) / 32, 256, 0, stream>>>(
            h, wgl, dinv, psP, pqP, ga, gw, gb, tp);
        agg_mfma<true><<<512, 256, 0, stream>>>(
            Ap, tp, dinv, bg + l * DD, psP, pqP, ga, gw, gb, h, psL, pqL);
    }
    apply_kernel<<<(BB * NN * DD / 4) / 256, 256, 0, stream>>>(
        h, psum + 2 * BB * DD, psq + 2 * BB * DD, ga, gw, gb, out);
}